// Round 7
// baseline (133.019 us; speedup 1.0000x reference)
//
#include <hip/hip_runtime.h>
#include <math.h>

// MoE router on MFMA: logits = (x @ W1^T + b1) @ W2^T + b2; softmax; top-2; masks.
// N=32768, D=1024, D_H=512, E=8, K=2.
//
// Split-fp16: x = xh+xl, W1 = wh+wl; h = xh*wh + xl*wh + xh*wl (3 MFMA passes,
// fp32 acc). W1 pre-split/pre-packed into 32x32x16 fragment order in d_ws (r4).
//
// Round-7: BK=32 (48 MFMA/wave per barrier, was 24 per 2 barriers) + mid-ktile
// s_barrier removed -- r6 showed per-iteration overhead (barrier convergence +
// first-ds_read latency) dominates at 2 waves/SIMD; amortize it, don't split it.
// B register-direct from L2 in-iteration (no cross-iter prefetch: saves VGPRs).
// A LDS double-buffer (32 KB) unioned with epilogue h_s (64 KB).

#define N_TOK 32768
#define D_IN  1024
#define D_H   512
#define N_EXP 8

#define BM      128
#define THREADS 512
#define NKT2    32            // 32-wide k-tiles
#define WSLOTS  (64 * 1024)   // W1 frag slots per hi/lo plane (16-wide tiles)

typedef _Float16 f16;
typedef __attribute__((ext_vector_type(4)))  _Float16 f16x4;
typedef __attribute__((ext_vector_type(8)))  _Float16 f16x8;
typedef __attribute__((ext_vector_type(16))) float    f32x16;

#define MFMA(a, b, c) __builtin_amdgcn_mfma_f32_32x32x16_f16((a), (b), (c), 0, 0, 0)

// ---- pre-kernel: split W1 into hi/lo f16 fragments in ws (verified r4-r6) ----
__global__ void split_w1(const float* __restrict__ W1,
                         f16* __restrict__ wsH, f16* __restrict__ wsL) {
    const int s = blockIdx.x * 256 + threadIdx.x;   // 0..65535
    const int kt  = s >> 10;
    const int ctg = (s >> 6) & 15;
    const int l   = s & 63;
    const int n   = ctg * 32 + (l & 31);
    const int k   = kt * 16 + (l >> 5) * 8;
    const float* src = &W1[(size_t)n * D_IN + k];
    float4 a0 = *(const float4*)src;
    float4 a1 = *(const float4*)(src + 4);
    f16x8 hi, lo;
#pragma unroll
    for (int j = 0; j < 4; ++j) {
        float v0 = ((const float*)&a0)[j];
        float v1 = ((const float*)&a1)[j];
        _Float16 h0 = (_Float16)v0, h1 = (_Float16)v1;
        hi[j] = h0;     hi[j + 4] = h1;
        lo[j] = (_Float16)(v0 - (float)h0);
        lo[j + 4] = (_Float16)(v1 - (float)h1);
    }
    *(f16x8*)&wsH[(size_t)s * 8] = hi;
    *(f16x8*)&wsL[(size_t)s * 8] = lo;
}

// ---- main kernel ----
__global__ __launch_bounds__(THREADS, 1)   // 1 block/CU -> 2 waves/SIMD -> 256 unified regs
void moe_router_mfma(const float* __restrict__ x,
                     const f16* __restrict__ wH,
                     const f16* __restrict__ wL,
                     const float* __restrict__ b1,
                     const float* __restrict__ W2,
                     const float* __restrict__ b2,
                     float* __restrict__ out)
{
    // A frag dbuf (2 buf x 2 plane x 4096 f16 = 32 KB) UNION epilogue h_s
    // ([32][512] f32 = 64 KB). A is dead in the epilogue; barrier-separated.
    __shared__ __align__(16) unsigned char SMEM[65536];
    __shared__ __align__(16) float W2s[N_EXP * D_H];     // 16 KB
    __shared__ __align__(16) float b1s[D_H];             // 2 KB
    __shared__ float b2s[N_EXP];

    f16*   AS  = (f16*)SMEM;      // [(buf*2+plane)*4096 + sub*2048 + slot*8]
    float* h_s = (float*)SMEM;    // epilogue only

    const int t    = threadIdx.x;
    const int w    = t >> 6;
    const int lane = t & 63;
    const int m0   = blockIdx.x * BM;

    // 8 accumulators: row-tile rt=0..3 x col c=0..1 (wave owns cols 2w,2w+1)
    f32x16 a0c0 = {}, a0c1 = {}, a1c0 = {}, a1c1 = {};
    f32x16 a2c0 = {}, a2c1 = {}, a3c0 = {}, a3c1 = {};

    // A staging geometry (verified r4-r6): thread t -> frag fA=t>>1, quarter qA=t&1.
    const int fA   = t >> 1;
    const int qA   = t & 1;
    const int rowA = (fA >> 6) * 32 + (fA & 31);
    const int kA   = ((fA >> 5) & 1) * 8 + qA * 4;
    const float* xsrc = x + (size_t)(m0 + rowA) * D_IN + kA;
    const int aDst = fA * 8 + qA * 4;   // f16 index within a sub-plane

    // B frag offsets for this wave (f16 elems within one 16-wide ktile plane)
    const size_t bOff0 = (size_t)(2 * w + 0) * 512 + (size_t)lane * 8;
    const size_t bOff1 = (size_t)(2 * w + 1) * 512 + (size_t)lane * 8;

    auto stageAwrite = [&](const float4& xv, int buf, int sub) {
        f16x4 hi, lo;
        float v[4] = {xv.x, xv.y, xv.z, xv.w};
#pragma unroll
        for (int j = 0; j < 4; ++j) {
            _Float16 h = (_Float16)v[j];
            hi[j] = h;
            lo[j] = (_Float16)(v[j] - (float)h);
        }
        *(f16x4*)&AS[(buf * 2 + 0) * 4096 + sub * 2048 + aDst] = hi;
        *(f16x4*)&AS[(buf * 2 + 1) * 4096 + sub * 2048 + aDst] = lo;
    };

    // ---- prologue: stage A ktile 0 (both 16-wide subs) ----
    {
        float4 xv0 = *(const float4*)xsrc;
        float4 xv1 = *(const float4*)(xsrc + 16);
        stageAwrite(xv0, 0, 0);
        stageAwrite(xv1, 0, 1);
    }
    __syncthreads();

    for (int ktt = 0; ktt < NKT2; ++ktt) {
        const int cur = ktt & 1;
        const int nxt = cur ^ 1;
        const size_t kb0 = (size_t)(2 * ktt) * 8192;
        const size_t kb1 = (size_t)(2 * ktt + 1) * 8192;

        // issue all global loads up front (L2-resident B; next-iter x)
        f16x8 B0h0 = *(const f16x8*)(wH + kb0 + bOff0);
        f16x8 B0h1 = *(const f16x8*)(wH + kb0 + bOff1);
        f16x8 B0l0 = *(const f16x8*)(wL + kb0 + bOff0);
        f16x8 B0l1 = *(const f16x8*)(wL + kb0 + bOff1);
        f16x8 B1h0 = *(const f16x8*)(wH + kb1 + bOff0);
        f16x8 B1h1 = *(const f16x8*)(wH + kb1 + bOff1);
        f16x8 B1l0 = *(const f16x8*)(wL + kb1 + bOff0);
        f16x8 B1l1 = *(const f16x8*)(wL + kb1 + bOff1);
        float4 xn0 = {0.f, 0.f, 0.f, 0.f}, xn1 = {0.f, 0.f, 0.f, 0.f};
        if (ktt + 1 < NKT2) {
            xn0 = *(const float4*)(xsrc + (size_t)(ktt + 1) * 32);
            xn1 = *(const float4*)(xsrc + (size_t)(ktt + 1) * 32 + 16);
        }

        const f16* ah = &AS[(cur * 2 + 0) * 4096];
        const f16* al = &AS[(cur * 2 + 1) * 4096];

        // ---- sub-tile 0 (k 0..15) ----
        {
            f16x8 ah0 = *(const f16x8*)&ah[(0 * 64 + lane) * 8];
            f16x8 al0 = *(const f16x8*)&al[(0 * 64 + lane) * 8];
            f16x8 ah1 = *(const f16x8*)&ah[(1 * 64 + lane) * 8];
            f16x8 al1 = *(const f16x8*)&al[(1 * 64 + lane) * 8];
            f16x8 ah2 = *(const f16x8*)&ah[(2 * 64 + lane) * 8];
            f16x8 al2 = *(const f16x8*)&al[(2 * 64 + lane) * 8];
            f16x8 ah3 = *(const f16x8*)&ah[(3 * 64 + lane) * 8];
            f16x8 al3 = *(const f16x8*)&al[(3 * 64 + lane) * 8];
            __builtin_amdgcn_s_setprio(1);
            a0c0 = MFMA(ah0, B0h0, a0c0); a0c0 = MFMA(al0, B0h0, a0c0); a0c0 = MFMA(ah0, B0l0, a0c0);
            a1c0 = MFMA(ah1, B0h0, a1c0); a1c0 = MFMA(al1, B0h0, a1c0); a1c0 = MFMA(ah1, B0l0, a1c0);
            a2c0 = MFMA(ah2, B0h0, a2c0); a2c0 = MFMA(al2, B0h0, a2c0); a2c0 = MFMA(ah2, B0l0, a2c0);
            a3c0 = MFMA(ah3, B0h0, a3c0); a3c0 = MFMA(al3, B0h0, a3c0); a3c0 = MFMA(ah3, B0l0, a3c0);
            a0c1 = MFMA(ah0, B0h1, a0c1); a0c1 = MFMA(al0, B0h1, a0c1); a0c1 = MFMA(ah0, B0l1, a0c1);
            a1c1 = MFMA(ah1, B0h1, a1c1); a1c1 = MFMA(al1, B0h1, a1c1); a1c1 = MFMA(ah1, B0l1, a1c1);
            a2c1 = MFMA(ah2, B0h1, a2c1); a2c1 = MFMA(al2, B0h1, a2c1); a2c1 = MFMA(ah2, B0l1, a2c1);
            a3c1 = MFMA(ah3, B0h1, a3c1); a3c1 = MFMA(al3, B0h1, a3c1); a3c1 = MFMA(ah3, B0l1, a3c1);
            __builtin_amdgcn_s_setprio(0);
        }
        // ---- sub-tile 1 (k 16..31) ----
        {
            f16x8 ah0 = *(const f16x8*)&ah[2048 + (0 * 64 + lane) * 8];
            f16x8 al0 = *(const f16x8*)&al[2048 + (0 * 64 + lane) * 8];
            f16x8 ah1 = *(const f16x8*)&ah[2048 + (1 * 64 + lane) * 8];
            f16x8 al1 = *(const f16x8*)&al[2048 + (1 * 64 + lane) * 8];
            f16x8 ah2 = *(const f16x8*)&ah[2048 + (2 * 64 + lane) * 8];
            f16x8 al2 = *(const f16x8*)&al[2048 + (2 * 64 + lane) * 8];
            f16x8 ah3 = *(const f16x8*)&ah[2048 + (3 * 64 + lane) * 8];
            f16x8 al3 = *(const f16x8*)&al[2048 + (3 * 64 + lane) * 8];
            __builtin_amdgcn_s_setprio(1);
            a0c0 = MFMA(ah0, B1h0, a0c0); a0c0 = MFMA(al0, B1h0, a0c0); a0c0 = MFMA(ah0, B1l0, a0c0);
            a1c0 = MFMA(ah1, B1h0, a1c0); a1c0 = MFMA(al1, B1h0, a1c0); a1c0 = MFMA(ah1, B1l0, a1c0);
            a2c0 = MFMA(ah2, B1h0, a2c0); a2c0 = MFMA(al2, B1h0, a2c0); a2c0 = MFMA(ah2, B1l0, a2c0);
            a3c0 = MFMA(ah3, B1h0, a3c0); a3c0 = MFMA(al3, B1h0, a3c0); a3c0 = MFMA(ah3, B1l0, a3c0);
            a0c1 = MFMA(ah0, B1h1, a0c1); a0c1 = MFMA(al0, B1h1, a0c1); a0c1 = MFMA(ah0, B1l1, a0c1);
            a1c1 = MFMA(ah1, B1h1, a1c1); a1c1 = MFMA(al1, B1h1, a1c1); a1c1 = MFMA(ah1, B1l1, a1c1);
            a2c1 = MFMA(ah2, B1h1, a2c1); a2c1 = MFMA(al2, B1h1, a2c1); a2c1 = MFMA(ah2, B1l1, a2c1);
            a3c1 = MFMA(ah3, B1h1, a3c1); a3c1 = MFMA(al3, B1h1, a3c1); a3c1 = MFMA(ah3, B1l1, a3c1);
            __builtin_amdgcn_s_setprio(0);
        }

        // stage A for next iter (other buffer; ordered before the barrier)
        if (ktt + 1 < NKT2) {
            stageAwrite(xn0, nxt, 0);
            stageAwrite(xn1, nxt, 1);
        }
        __syncthreads();   // single barrier per 32-wide ktile
    }

    // ---- epilogue (verified r4-r6) ----
    ((float4*)W2s)[t * 2]     = ((const float4*)W2)[t * 2];
    ((float4*)W2s)[t * 2 + 1] = ((const float4*)W2)[t * 2 + 1];
    if (t < D_H / 4) ((float4*)b1s)[t] = ((const float4*)b1)[t];
    if (t < N_EXP) b2s[t] = b2[t];
    __syncthreads();

    const int n0  = w * 64 + (lane & 31);   // C/D layout: col = lane&31
    const int n1  = n0 + 32;
    const float bn0 = b1s[n0];
    const float bn1 = b1s[n1];

    float* out_logits = out;
    float* out_w      = out + (size_t)N_TOK * N_EXP;
    float* out_i      = out_w + (size_t)N_TOK * 2;
    float* out_m      = out_i + (size_t)N_TOK * 2;

    auto reduce_rows = [&](int rt) {
#pragma unroll
        for (int rr2 = 0; rr2 < 4; ++rr2) {
            const int rl   = w * 4 + rr2;            // 8 waves x 4 = 32 rows
            const int grow = m0 + rt * 32 + rl;
            float4 ha = *(const float4*)&h_s[rl * 512 + lane * 4];
            float4 hb = *(const float4*)&h_s[rl * 512 + 256 + lane * 4];
            float v1 = -3.4e38f, v2 = -3.4e38f;
            int   i1 = 0, i2 = 0;
            float pls[8];
#pragma unroll
            for (int e = 0; e < N_EXP; ++e) {
                float4 wa = *(const float4*)&W2s[e * D_H + lane * 4];
                float4 wb = *(const float4*)&W2s[e * D_H + 256 + lane * 4];
                float s = ha.x * wa.x;
                s = fmaf(ha.y, wa.y, s);
                s = fmaf(ha.z, wa.z, s);
                s = fmaf(ha.w, wa.w, s);
                s = fmaf(hb.x, wb.x, s);
                s = fmaf(hb.y, wb.y, s);
                s = fmaf(hb.z, wb.z, s);
                s = fmaf(hb.w, wb.w, s);
#pragma unroll
                for (int off = 1; off < 64; off <<= 1)
                    s += __shfl_xor(s, off);
                s += b2s[e];
                pls[e] = s;
                if (s > v1)      { v2 = v1; i2 = i1; v1 = s; i1 = e; }
                else if (s > v2) { v2 = s;  i2 = e; }
            }
            const float rr   = expf(v2 - v1);
            const float wden = 1.f / (1.f + rr);
            if (lane == 0) {
                float4 lo4 = {pls[0], pls[1], pls[2], pls[3]};
                float4 hi4 = {pls[4], pls[5], pls[6], pls[7]};
                *(float4*)&out_logits[(size_t)grow * N_EXP]     = lo4;
                *(float4*)&out_logits[(size_t)grow * N_EXP + 4] = hi4;
                float2 wv = {wden, rr * wden};
                *(float2*)&out_w[(size_t)grow * 2] = wv;
                float2 iv = {(float)i1, (float)i2};
                *(float2*)&out_i[(size_t)grow * 2] = iv;
            }
            if (lane < 16) {
                const int e   = lane >> 1;
                const int kk  = lane & 1;
                const int sel = kk ? i2 : i1;
                out_m[((size_t)(e * 2 + kk)) * N_TOK + grow] = (sel == e) ? 1.0f : 0.0f;
            }
        }
    };

    // C/D row map (verified): in-tile row = (rr&3) + 8*(rr>>2) + 4*(lane>>5)
#define DO_GROUP(AC0, AC1, RT) do {                                            \
        _Pragma("unroll")                                                      \
        for (int rr = 0; rr < 16; ++rr) {                                      \
            const int rl = (rr & 3) + 8 * (rr >> 2) + 4 * (lane >> 5);         \
            h_s[rl * 512 + n0] = AC0[rr] + bn0;                                \
            h_s[rl * 512 + n1] = AC1[rr] + bn1;                                \
        }                                                                      \
        __syncthreads();                                                       \
        reduce_rows(RT);                                                       \
        __syncthreads();                                                       \
    } while (0)

    DO_GROUP(a0c0, a0c1, 0);
    DO_GROUP(a1c0, a1c1, 1);
    DO_GROUP(a2c0, a2c1, 2);
    DO_GROUP(a3c0, a3c1, 3);
#undef DO_GROUP
}

extern "C" void kernel_launch(void* const* d_in, const int* in_sizes, int n_in,
                              void* d_out, int out_size, void* d_ws, size_t ws_size,
                              hipStream_t stream) {
    const float* x  = (const float*)d_in[0];
    const float* W1 = (const float*)d_in[1];
    const float* b1 = (const float*)d_in[2];
    const float* W2 = (const float*)d_in[3];
    const float* b2 = (const float*)d_in[4];
    float* out = (float*)d_out;

    f16* wsH = (f16*)d_ws;                       // 1 MB
    f16* wsL = wsH + (size_t)WSLOTS * 8;         // 1 MB

    split_w1<<<WSLOTS / 256, 256, 0, stream>>>(W1, wsH, wsL);
    moe_router_mfma<<<N_TOK / BM, THREADS, 0, stream>>>(x, wsH, wsL, b1, W2, b2, out);
}